// Round 4
// baseline (221.967 us; speedup 1.0000x reference)
//
#include <hip/hip_runtime.h>

#define SEQ 4096
#define KDIM 1024
#define NQKV 3072
#define BK 32

typedef __bf16 bf16x8 __attribute__((ext_vector_type(8)));
typedef float  f32x4  __attribute__((ext_vector_type(4)));

#define WAITV(n) asm volatile("s_waitcnt vmcnt(" #n ")" ::: "memory")
#define BAR()    asm volatile("s_barrier" ::: "memory")

__device__ __forceinline__ unsigned short f2b(float f) {
    unsigned int u = __float_as_uint(f);
    u += 0x7FFFu + ((u >> 16) & 1u);   // round-to-nearest-even
    return (unsigned short)(u >> 16);
}
__device__ __forceinline__ float b2f(unsigned short h) {
    return __uint_as_float(((unsigned int)h) << 16);
}

__device__ __forceinline__ void gld_lds16(const unsigned short* g, unsigned short* l) {
    __builtin_amdgcn_global_load_lds(
        (const __attribute__((address_space(1))) void*)g,
        (__attribute__((address_space(3))) void*)l, 16, 0, 0);
}

// ---------------------------------------------------------------------------
// Shared pieces: XOR-swizzled staging + fragment reads + MFMA compute.
// (128x128 tile, 4 waves, 256 threads — the proven r1 geometry.)
// ---------------------------------------------------------------------------
__device__ __forceinline__ void stage_tiles(
    const unsigned short* Ag, int lda, const unsigned short* Bg, int ldb,
    int k0, unsigned short* sA, unsigned short* sB, int wave, int lane)
{
    #pragma unroll
    for (int i = 0; i < 2; ++i) {
        int c = wave * 128 + i * 64 + lane;        // chunk id 0..511
        int row = c >> 2, slot = c & 3;
        int p = slot ^ ((row >> 1) & 3);           // XOR-swizzled piece
        gld_lds16(Ag + row * lda + k0 + p * 8, sA + (wave * 2 + i) * 512);
        gld_lds16(Bg + row * ldb + k0 + p * 8, sB + (wave * 2 + i) * 512);
    }
}

__device__ __forceinline__ const unsigned short* frag_addr(
    const unsigned short* s, int row, int quad)
{
    return s + row * 32 + (quad ^ ((row >> 1) & 3)) * 8;
}

__device__ __forceinline__ void compute_tile(
    const unsigned short* sA, const unsigned short* sB, f32x4 acc[4][4],
    int wm, int wn, int lr, int quad)
{
    bf16x8 af[4], bq[4];
    #pragma unroll
    for (int i = 0; i < 4; ++i)
        af[i] = *(const bf16x8*)frag_addr(sA, wm + 16 * i + lr, quad);
    #pragma unroll
    for (int j = 0; j < 4; ++j)
        bq[j] = *(const bf16x8*)frag_addr(sB, wn + 16 * j + lr, quad);
    #pragma unroll
    for (int i = 0; i < 4; ++i)
        #pragma unroll
        for (int j = 0; j < 4; ++j)
            acc[i][j] = __builtin_amdgcn_mfma_f32_16x16x32_bf16(af[i], bq[j], acc[i][j], 0, 0, 0);
}

// 3-stage vmcnt-gated pipe (48 KB LDS) — for the K=1024 GEMMs (qvk, score).
__device__ __forceinline__ void mfma_pipe(
    const unsigned short* Ag, int lda, const unsigned short* Bg, int ldb,
    int kLen, unsigned short* lds, f32x4 acc[4][4])
{
    const int tid  = threadIdx.x;
    const int wave = tid >> 6, lane = tid & 63;
    const int lr   = lane & 15, quad = lane >> 4;
    const int wm   = (wave >> 1) * 64, wn = (wave & 1) * 64;
    const int niter = kLen >> 5;

    #pragma unroll
    for (int s = 0; s < 2; ++s)
        if (s < niter)
            stage_tiles(Ag, lda, Bg, ldb, s * BK,
                        lds + s * 8192, lds + s * 8192 + 4096, wave, lane);

    #pragma unroll 1
    for (int k = 0; k < niter; ++k) {
        if (k + 1 < niter) WAITV(4);    // stage k done; k+1 stays in flight
        else               WAITV(0);
        BAR();
        if (k + 2 < niter) {
            const int s = (k + 2) % 3;
            stage_tiles(Ag, lda, Bg, ldb, (k + 2) * BK,
                        lds + s * 8192, lds + s * 8192 + 4096, wave, lane);
        }
        const int c = k % 3;
        compute_tile(lds + c * 8192, lds + c * 8192 + 4096, acc, wm, wn, lr, quad);
    }
}

// 2-stage __syncthreads double-buffer (32 KB LDS) — R4-proven, for pv.
__device__ __forceinline__ void mfma_db(
    const unsigned short* Ag, int lda, const unsigned short* Bg, int ldb,
    int kLen, unsigned short* lds, f32x4 acc[4][4])
{
    const int tid  = threadIdx.x;
    const int wave = tid >> 6, lane = tid & 63;
    const int lr   = lane & 15, quad = lane >> 4;
    const int wm   = (wave >> 1) * 64, wn = (wave & 1) * 64;
    unsigned short* sA0 = lds;
    unsigned short* sB0 = lds + 4096;
    unsigned short* sA1 = lds + 8192;
    unsigned short* sB1 = lds + 12288;

    stage_tiles(Ag, lda, Bg, ldb, 0, sA0, sB0, wave, lane);
    int k = BK;
    #pragma unroll 1
    for (; k + BK < kLen; k += 2 * BK) {
        __syncthreads();
        stage_tiles(Ag, lda, Bg, ldb, k, sA1, sB1, wave, lane);
        compute_tile(sA0, sB0, acc, wm, wn, lr, quad);
        __syncthreads();
        stage_tiles(Ag, lda, Bg, ldb, k + BK, sA0, sB0, wave, lane);
        compute_tile(sA1, sB1, acc, wm, wn, lr, quad);
    }
    if (k < kLen) {
        __syncthreads();
        stage_tiles(Ag, lda, Bg, ldb, k, sA1, sB1, wave, lane);
        compute_tile(sA0, sB0, acc, wm, wn, lr, quad);
        __syncthreads();
        compute_tile(sA1, sB1, acc, wm, wn, lr, quad);
    } else {
        __syncthreads();
        compute_tile(sA0, sB0, acc, wm, wn, lr, quad);
    }
}

__device__ __forceinline__ void zero_acc(f32x4 acc[4][4]) {
    const f32x4 z = {0.f, 0.f, 0.f, 0.f};
    #pragma unroll
    for (int i = 0; i < 4; ++i)
        #pragma unroll
        for (int j = 0; j < 4; ++j) acc[i][j] = z;
}

// ---------------------------------------------------------------------------
// Epilogue: wave-private LDS restage -> 16B coalesced bf16 stores.
// ---------------------------------------------------------------------------
__device__ __forceinline__ void store_rows_bf16(
    f32x4 acc[4][4], unsigned short* Cw, int ld, unsigned short* lw, int lane)
{
    const int lr = lane & 15, quad = lane >> 4;
    #pragma unroll
    for (int i = 0; i < 4; ++i) {
        #pragma unroll
        for (int j = 0; j < 4; ++j)
            #pragma unroll
            for (int r = 0; r < 4; ++r)
                lw[(quad * 4 + r) * 72 + j * 16 + lr] = f2b(acc[i][j][r]);
        #pragma unroll
        for (int t = 0; t < 2; ++t) {
            int chunk = t * 64 + lane;          // 0..127
            int rl = chunk >> 3, c8 = chunk & 7;
            uint4 v = *(const uint4*)(lw + rl * 72 + c8 * 8);
            *(uint4*)(Cw + (16 * i + rl) * ld + c8 * 8) = v;
        }
    }
}

// Transposed (Vt[d][s]): each lane stores 8 consecutive s for one d.
__device__ __forceinline__ void store_cols_bf16(
    f32x4 acc[4][4], unsigned short* Vw, unsigned short* lw, int lane)
{
    const int lr = lane & 15, quad = lane >> 4;
    #pragma unroll
    for (int ip = 0; ip < 2; ++ip) {            // 32 s-rows per pass
        #pragma unroll
        for (int ii = 0; ii < 2; ++ii)
            #pragma unroll
            for (int j = 0; j < 4; ++j)
                #pragma unroll
                for (int r = 0; r < 4; ++r)
                    lw[(j * 16 + lr) * 40 + ii * 16 + quad * 4 + r] = f2b(acc[ip * 2 + ii][j][r]);
        #pragma unroll
        for (int t = 0; t < 4; ++t) {
            int chunk = t * 64 + lane;          // 0..255
            int col = chunk >> 2, c8 = chunk & 3;
            uint4 v = *(const uint4*)(lw + col * 40 + c8 * 8);
            *(uint4*)(Vw + col * SEQ + ip * 32 + c8 * 8) = v;
        }
    }
}

// ---------------------------------------------------------------------------
// Kernel 0: fused prep. [0,4096): x->bf16; [4096,8192): zero d_out;
// [8192,11264): W transpose; block 11264: zero lrow[4096].
// ---------------------------------------------------------------------------
__global__ __launch_bounds__(256) void prep(
    const float* __restrict__ x, unsigned short* __restrict__ Xb,
    const float* __restrict__ W, unsigned short* __restrict__ Wt,
    float4* __restrict__ out, float4* __restrict__ lrow)
{
    __shared__ float tile[32][33];
    const int b = blockIdx.x, tid = threadIdx.x;
    if (b < 4096) {
        int i = (b * 256 + tid) * 4;
        float4 v = *(const float4*)(x + i);
        ushort4 o;
        o.x = f2b(v.x); o.y = f2b(v.y); o.z = f2b(v.z); o.w = f2b(v.w);
        *(ushort4*)(Xb + i) = o;
    } else if (b < 8192) {
        const float4 z = {0.f, 0.f, 0.f, 0.f};
        out[(b - 4096) * 256 + tid] = z;
    } else if (b < 11264) {
        const int bb = b - 8192;
        const int n0 = (bb % 96) * 32, k0 = (bb / 96) * 32;
        const int c = tid & 31, r0 = tid >> 5;
        #pragma unroll
        for (int r = r0; r < 32; r += 8)
            tile[r][c] = W[(k0 + r) * NQKV + n0 + c];
        __syncthreads();
        #pragma unroll
        for (int r = r0; r < 32; r += 8)
            Wt[(n0 + r) * KDIM + k0 + c] = f2b(tile[c][r]);
    } else {
        const float4 z = {0.f, 0.f, 0.f, 0.f};
        #pragma unroll
        for (int k = 0; k < 4; ++k) lrow[tid * 4 + k] = z;
    }
}

// ---------------------------------------------------------------------------
// Kernel 1: qvk = Xb @ Wt^T -> Q rows, K rows, V transposed (Vt[d][s])
// Grid (m=32, n=24): lin%8 = m%8 -> same Xb tile co-resident per XCD L2.
// ---------------------------------------------------------------------------
__global__ __launch_bounds__(256) void qvk_gemm(
    const unsigned short* __restrict__ Xb, const unsigned short* __restrict__ Wt,
    unsigned short* __restrict__ Qb, unsigned short* __restrict__ Kb,
    unsigned short* __restrict__ Vt)
{
    __shared__ __align__(16) unsigned short lds[24576];   // 48 KiB
    const int m0 = blockIdx.x * 128;
    const int n0 = blockIdx.y * 128;
    f32x4 acc[4][4];
    zero_acc(acc);
    mfma_pipe(Xb + m0 * KDIM, KDIM, Wt + n0 * KDIM, KDIM, KDIM, lds, acc);
    __syncthreads();

    const int lane = threadIdx.x & 63, wave = threadIdx.x >> 6;
    const int wm = (wave >> 1) * 64, wn = (wave & 1) * 64;
    unsigned short* lw = lds + wave * 2560;
    const int region = n0 >> 10;
    const int nloc = n0 & 1023;
    if (region == 0)
        store_rows_bf16(acc, Qb + (m0 + wm) * KDIM + nloc + wn, KDIM, lw, lane);
    else if (region == 2)
        store_rows_bf16(acc, Kb + (m0 + wm) * KDIM + nloc + wn, KDIM, lw, lane);
    else
        store_cols_bf16(acc, Vt + (nloc + wn) * SEQ + m0 + wm, lw, lane);
}

// ---------------------------------------------------------------------------
// Kernel 2: fused score+exp. P = exp((Q@K^T)/32) causal (no max-sub: |s|<=16
// by Cauchy-Schwarz). Row sums atomicAdd into lrow; P bf16 to Sb.
// Packed triangular 1-D grid: exactly 528 live blocks (no dead dispatches).
// ---------------------------------------------------------------------------
__global__ __launch_bounds__(256) void score_exp_gemm(
    const unsigned short* __restrict__ Qb, const unsigned short* __restrict__ Kb,
    unsigned short* __restrict__ Sb, float* __restrict__ lrow)
{
    __shared__ __align__(16) unsigned short lds[24576];
    const int L = blockIdx.x;                   // 0..527
    int bm = (int)((sqrtf(8.0f * (float)L + 1.0f) - 1.0f) * 0.5f);
    while ((bm + 1) * (bm + 2) / 2 <= L) ++bm;  // fix float rounding
    while (bm * (bm + 1) / 2 > L) --bm;
    const int bn = L - bm * (bm + 1) / 2;
    const int m0 = bm * 128, n0 = bn * 128;

    f32x4 acc[4][4];
    zero_acc(acc);
    mfma_pipe(Qb + m0 * KDIM, KDIM, Kb + n0 * KDIM, KDIM, KDIM, lds, acc);

    const int lane = threadIdx.x & 63, wave = threadIdx.x >> 6;
    const int lr = lane & 15, quad = lane >> 4;
    const int wm = (wave >> 1) * 64, wn = (wave & 1) * 64;
    #pragma unroll
    for (int i = 0; i < 4; ++i)
        #pragma unroll
        for (int j = 0; j < 4; ++j)
            #pragma unroll
            for (int r = 0; r < 4; ++r) {
                float v = __expf(acc[i][j][r] * 0.03125f);
                if (bm == bn) {
                    int row = wm + 16 * i + quad * 4 + r;
                    int col = wn + 16 * j + lr;
                    if (col > row) v = 0.f;
                }
                acc[i][j][r] = v;
            }
    #pragma unroll
    for (int i = 0; i < 4; ++i)
        #pragma unroll
        for (int r = 0; r < 4; ++r) {
            float s = acc[i][0][r] + acc[i][1][r] + acc[i][2][r] + acc[i][3][r];
            s += __shfl_xor(s, 1, 16);
            s += __shfl_xor(s, 2, 16);
            s += __shfl_xor(s, 4, 16);
            s += __shfl_xor(s, 8, 16);
            if (lr == 0)
                atomicAdd(&lrow[m0 + wm + 16 * i + quad * 4 + r], s);
        }
    __syncthreads();
    store_rows_bf16(acc, Sb + (m0 + wm) * SEQ + n0 + wn, SEQ, lds + wave * 2560, lane);
}

// ---------------------------------------------------------------------------
// Kernel 3: out = (P @ V) / l, split-K in 512-wide chunks (atomic depth <=8).
// Grid dim3(x=n(8), y=144): 1152 blocks -> 4.5 balanced device rounds.
// y decode (reversed: big-K chunks dispatch first, LPT):
//   group g = mm>>2 (g=0..7) has g+1 chunks per mm; group offset 2g(g+1).
// ---------------------------------------------------------------------------
__global__ __launch_bounds__(256) void pv_gemm(
    const unsigned short* __restrict__ Sb, const unsigned short* __restrict__ Vt,
    const float* __restrict__ lrow, float* __restrict__ out)
{
    __shared__ __align__(16) unsigned short lds[16384];   // 32 KiB
    const int n0 = blockIdx.x * 128;
    const int y = 143 - (int)blockIdx.y;        // reversed: largest mm first
    int g = 0;
    while (2 * (g + 1) * (g + 2) <= y) ++g;     // find group: 2g(g+1) <= y
    const int r = y - 2 * g * (g + 1);
    const int mm = 4 * g + r / (g + 1);
    const int c  = r % (g + 1);
    const int m0 = mm * 128;
    const int kstart = c * 512;
    const int kend = min((mm + 1) * 128, kstart + 512);
    const int nchunks = g + 1;

    f32x4 acc[4][4];
    zero_acc(acc);
    mfma_db(Sb + m0 * SEQ + kstart, SEQ, Vt + n0 * SEQ + kstart, SEQ,
            kend - kstart, lds, acc);

    const int lane = threadIdx.x & 63, wave = threadIdx.x >> 6;
    const int lr = lane & 15, quad = lane >> 4;
    const int wm = (wave >> 1) * 64, wn = (wave & 1) * 64;
    #pragma unroll
    for (int i = 0; i < 4; ++i) {
        const int rbase = m0 + wm + 16 * i + quad * 4;
        const float4 l4 = *(const float4*)(lrow + rbase);
        float inv[4] = {1.0f / l4.x, 1.0f / l4.y, 1.0f / l4.z, 1.0f / l4.w};
        #pragma unroll
        for (int j = 0; j < 4; ++j) {
            const int col = n0 + wn + 16 * j + lr;
            if (nchunks == 1) {
                #pragma unroll
                for (int r2 = 0; r2 < 4; ++r2)
                    out[(rbase + r2) * KDIM + col] = acc[i][j][r2] * inv[r2];
            } else {
                #pragma unroll
                for (int r2 = 0; r2 < 4; ++r2)
                    atomicAdd(&out[(rbase + r2) * KDIM + col], acc[i][j][r2] * inv[r2]);
            }
        }
    }
}

// ---------------------------------------------------------------------------
extern "C" void kernel_launch(void* const* d_in, const int* in_sizes, int n_in,
                              void* d_out, int out_size, void* d_ws, size_t ws_size,
                              hipStream_t stream) {
    const float* x = (const float*)d_in[0];   // [4096][1024]
    const float* W = (const float*)d_in[1];   // [1024][3072]
    float* out = (float*)d_out;               // [4096][1024]
    char* ws = (char*)d_ws;

    unsigned short* Xb = (unsigned short*)(ws);                     //  8 MiB
    unsigned short* Wt = (unsigned short*)(ws + 8388608);           //  6 MiB
    unsigned short* Qb = (unsigned short*)(ws + 14680064);          //  8 MiB
    unsigned short* Kb = (unsigned short*)(ws + 23068672);          //  8 MiB
    unsigned short* Vt = (unsigned short*)(ws + 31457280);          //  8 MiB
    unsigned short* Sb = (unsigned short*)(ws + 39845888);          // 32 MiB
    float*        lrow = (float*)(ws + 73400320);                   // 16 KiB

    prep          <<<11265, 256, 0, stream>>>(x, Xb, W, Wt, (float4*)out, (float4*)lrow);
    qvk_gemm      <<<dim3(SEQ / 128, NQKV / 128), 256, 0, stream>>>(Xb, Wt, Qb, Kb, Vt);
    score_exp_gemm<<<528, 256, 0, stream>>>(Qb, Kb, Sb, lrow);
    pv_gemm       <<<dim3(KDIM / 128, 144), 256, 0, stream>>>(Sb, Vt, lrow, out);
}

// Round 5
// 198.040 us; speedup vs baseline: 1.1208x; 1.1208x over previous
//
#include <hip/hip_runtime.h>

#define SEQ 4096
#define KDIM 1024
#define NQKV 3072
#define BK 32

typedef __bf16 bf16x8 __attribute__((ext_vector_type(8)));
typedef float  f32x4  __attribute__((ext_vector_type(4)));

#define WAITV(n) asm volatile("s_waitcnt vmcnt(" #n ")" ::: "memory")
#define BAR()    asm volatile("s_barrier" ::: "memory")
#define SETP(n)  __builtin_amdgcn_s_setprio(n)

__device__ __forceinline__ unsigned short f2b(float f) {
    unsigned int u = __float_as_uint(f);
    u += 0x7FFFu + ((u >> 16) & 1u);   // round-to-nearest-even
    return (unsigned short)(u >> 16);
}

__device__ __forceinline__ void gld_lds16(const unsigned short* g, unsigned short* l) {
    __builtin_amdgcn_global_load_lds(
        (const __attribute__((address_space(1))) void*)g,
        (__attribute__((address_space(3))) void*)l, 16, 0, 0);
}

// Proven conflict-free fragment address (32-col unit, XOR piece swizzle).
__device__ __forceinline__ const unsigned short* frag_addr(
    const unsigned short* s, int row, int quad)
{
    return s + row * 32 + (quad ^ ((row >> 1) & 3)) * 8;
}

// ===========================================================================
// 256x256 8-phase pipe (512 thr, 8 waves 2Mx4N, BK=64 as 2x32-col units,
// 128 KiB LDS = 2 dbuf x {A,B} x 2 halves x [128 rows x 32 cols]).
// Unit base (ushorts): d*32768 + (B?16384:0) + (kk*2+h)*4096.
// Stage: 1 gld_lds/thread per unit; thread tid -> row=tid>>2, piece
// p = (tid&3)^((row>>1)&3); dst = unit + wave*512 (linear, wave-uniform).
// ===========================================================================
__device__ __forceinline__ void stgU(
    const unsigned short* G, int ldg, int tOff, int kk, int h,
    unsigned short* unit, int tid)
{
    int row = tid >> 2, sl = tid & 3;
    int p = sl ^ ((row >> 1) & 3);
    gld_lds16(G + (h * 128 + row) * ldg + tOff + kk * 32 + p * 8,
              unit + (tid >> 6) * 512);
}

__device__ __forceinline__ void rdA(
    bf16x8 a[4], const unsigned short* u, int ih, int lr, int quad)
{
    #pragma unroll
    for (int i = 0; i < 4; ++i)
        a[i] = *(const bf16x8*)frag_addr(u, ih * 64 + 16 * i + lr, quad);
}
__device__ __forceinline__ void rdB(
    bf16x8 b[4], const unsigned short* u, int bRow, int lr, int quad)
{
    #pragma unroll
    for (int j = 0; j < 4; ++j)
        b[j] = *(const bf16x8*)frag_addr(u, bRow + 16 * j + lr, quad);
}
__device__ __forceinline__ void mm8(
    f32x4 acc[8][4], const bf16x8 a[4], const bf16x8 b[4], int io)
{
    #pragma unroll
    for (int i = 0; i < 4; ++i)
        #pragma unroll
        for (int j = 0; j < 4; ++j)
            acc[io + i][j] = __builtin_amdgcn_mfma_f32_16x16x32_bf16(
                a[i], b[j], acc[io + i][j], 0, 0, 0);
}

// K fixed = 1024 (niter = 8 iters x 128-K). Phase/stage/vmcnt schedule:
//  consume: p1-2 d0kk0 | p3-4 d0kk1 | p5-6 d1kk0 | p7-8 d1kk1
//  stage:   p1-2 t(2u+1)kk1 | p3-4 t(2u+2)kk0 | p5-6 t(2u+2)kk1 | p7-8 t(2u+3)kk0
//  each stage targets units freed >=1 post-MFMA barrier earlier.
//  WAITV(4) at p4/p8 certifies everything except the 2 newest stage-phases.
__device__ __forceinline__ void mfma_pipe8(
    const unsigned short* Ag, int lda, const unsigned short* Bg, int ldb,
    unsigned short* lds, f32x4 acc[8][4])
{
    const int tid  = threadIdx.x;
    const int wave = tid >> 6, lane = tid & 63;
    const int lr   = lane & 15, quad = lane >> 4;
    const int mg   = wave >> 2;          // A half owned by this wave
    const int ng   = wave & 3;
    const int hB   = ng >> 1, bRow = (ng & 1) * 64;
    const int niter = 8;

    // read-unit bases for this wave
    const unsigned short* rA_d0k0 = lds + mg * 4096;
    const unsigned short* rA_d0k1 = lds + 8192 + mg * 4096;
    const unsigned short* rA_d1k0 = lds + 32768 + mg * 4096;
    const unsigned short* rA_d1k1 = lds + 40960 + mg * 4096;
    const unsigned short* rB_d0k0 = lds + 16384 + hB * 4096;
    const unsigned short* rB_d0k1 = lds + 24576 + hB * 4096;
    const unsigned short* rB_d1k0 = lds + 49152 + hB * 4096;
    const unsigned short* rB_d1k1 = lds + 57344 + hB * 4096;

    // prologue: tile0 full (8 loads) + tile1 kk0 (4 loads)
    stgU(Ag, lda, 0, 0, 0, lds + 0,     tid);
    stgU(Ag, lda, 0, 0, 1, lds + 4096,  tid);
    stgU(Bg, ldb, 0, 0, 0, lds + 16384, tid);
    stgU(Bg, ldb, 0, 0, 1, lds + 20480, tid);
    stgU(Ag, lda, 0, 1, 0, lds + 8192,  tid);
    stgU(Ag, lda, 0, 1, 1, lds + 12288, tid);
    stgU(Bg, ldb, 0, 1, 0, lds + 24576, tid);
    stgU(Bg, ldb, 0, 1, 1, lds + 28672, tid);
    stgU(Ag, lda, 64, 0, 0, lds + 32768, tid);
    stgU(Ag, lda, 64, 0, 1, lds + 36864, tid);
    stgU(Bg, ldb, 64, 0, 0, lds + 49152, tid);
    stgU(Bg, ldb, 64, 0, 1, lds + 53248, tid);
    WAITV(4);           // tile0 certified; tile1-kk0 stays in flight
    BAR();

    bf16x8 a[4], b[4];

    #pragma unroll 1
    for (int u = 0; u < niter; ++u) {
        const bool pre = (u + 1 < niter);
        const int t1o = (2 * u + 1) * 64;
        const int t2o = (2 * u + 2) * 64;
        const int t3o = (2 * u + 3) * 64;

        // p1: d0kk0 ih0 ; stage A(t1,kk1)->d1kk1
        rdB(b, rB_d0k0, bRow, lr, quad);
        rdA(a, rA_d0k0, 0, lr, quad);
        stgU(Ag, lda, t1o, 1, 0, lds + 40960, tid);
        stgU(Ag, lda, t1o, 1, 1, lds + 45056, tid);
        BAR(); SETP(1); mm8(acc, a, b, 0); SETP(0); BAR();

        // p2: d0kk0 ih1 ; stage B(t1,kk1)->d1kk1
        rdA(a, rA_d0k0, 1, lr, quad);
        stgU(Bg, ldb, t1o, 1, 0, lds + 57344, tid);
        stgU(Bg, ldb, t1o, 1, 1, lds + 61440, tid);
        BAR(); SETP(1); mm8(acc, a, b, 4); SETP(0); BAR();

        // p3: d0kk1 ih0 ; stage A(t2,kk0)->d0kk0 (freed after p2)
        rdB(b, rB_d0k1, bRow, lr, quad);
        rdA(a, rA_d0k1, 0, lr, quad);
        if (pre) {
            stgU(Ag, lda, t2o, 0, 0, lds + 0,    tid);
            stgU(Ag, lda, t2o, 0, 1, lds + 4096, tid);
        }
        BAR(); SETP(1); mm8(acc, a, b, 0); SETP(0); BAR();

        // p4: d0kk1 ih1 ; stage B(t2,kk0) ; certify tile(2u+1)
        rdA(a, rA_d0k1, 1, lr, quad);
        if (pre) {
            stgU(Bg, ldb, t2o, 0, 0, lds + 16384, tid);
            stgU(Bg, ldb, t2o, 0, 1, lds + 20480, tid);
        }
        BAR(); SETP(1); mm8(acc, a, b, 4); SETP(0);
        if (pre) WAITV(4); else WAITV(0);
        BAR();

        // p5: d1kk0 ih0 ; stage A(t2,kk1)->d0kk1 (freed after p4)
        rdB(b, rB_d1k0, bRow, lr, quad);
        rdA(a, rA_d1k0, 0, lr, quad);
        if (pre) {
            stgU(Ag, lda, t2o, 1, 0, lds + 8192,  tid);
            stgU(Ag, lda, t2o, 1, 1, lds + 12288, tid);
        }
        BAR(); SETP(1); mm8(acc, a, b, 0); SETP(0); BAR();

        // p6: d1kk0 ih1 ; stage B(t2,kk1)
        rdA(a, rA_d1k0, 1, lr, quad);
        if (pre) {
            stgU(Bg, ldb, t2o, 1, 0, lds + 24576, tid);
            stgU(Bg, ldb, t2o, 1, 1, lds + 28672, tid);
        }
        BAR(); SETP(1); mm8(acc, a, b, 4); SETP(0); BAR();

        // p7: d1kk1 ih0 ; stage A(t3,kk0)->d1kk0 (freed after p6)
        rdB(b, rB_d1k1, bRow, lr, quad);
        rdA(a, rA_d1k1, 0, lr, quad);
        if (pre) {
            stgU(Ag, lda, t3o, 0, 0, lds + 32768, tid);
            stgU(Ag, lda, t3o, 0, 1, lds + 36864, tid);
        }
        BAR(); SETP(1); mm8(acc, a, b, 0); SETP(0); BAR();

        // p8: d1kk1 ih1 ; stage B(t3,kk0) ; certify tile(2u+2)
        rdA(a, rA_d1k1, 1, lr, quad);
        if (pre) {
            stgU(Bg, ldb, t3o, 0, 0, lds + 49152, tid);
            stgU(Bg, ldb, t3o, 0, 1, lds + 53248, tid);
        }
        BAR(); SETP(1); mm8(acc, a, b, 4); SETP(0);
        if (pre) WAITV(4);
        BAR();
    }
}

__device__ __forceinline__ void zero_acc8(f32x4 acc[8][4]) {
    const f32x4 z = {0.f, 0.f, 0.f, 0.f};
    #pragma unroll
    for (int i = 0; i < 8; ++i)
        #pragma unroll
        for (int j = 0; j < 4; ++j) acc[i][j] = z;
}
__device__ __forceinline__ void zero_acc4(f32x4 acc[4][4]) {
    const f32x4 z = {0.f, 0.f, 0.f, 0.f};
    #pragma unroll
    for (int i = 0; i < 4; ++i)
        #pragma unroll
        for (int j = 0; j < 4; ++j) acc[i][j] = z;
}

// ---------------------------------------------------------------------------
// Epilogues (r2-verified 8x4 versions; r1-verified 4x4 for pv).
// ---------------------------------------------------------------------------
__device__ __forceinline__ void store_rows8(
    f32x4 acc[8][4], unsigned short* Cw, int ld, unsigned short* lw, int lane)
{
    const int lr = lane & 15, quad = lane >> 4;
    #pragma unroll
    for (int i = 0; i < 8; ++i) {
        #pragma unroll
        for (int j = 0; j < 4; ++j)
            #pragma unroll
            for (int r = 0; r < 4; ++r)
                lw[(quad * 4 + r) * 72 + j * 16 + lr] = f2b(acc[i][j][r]);
        #pragma unroll
        for (int t = 0; t < 2; ++t) {
            int chunk = t * 64 + lane;
            int rl = chunk >> 3, c8 = chunk & 7;
            uint4 v = *(const uint4*)(lw + rl * 72 + c8 * 8);
            *(uint4*)(Cw + (16 * i + rl) * ld + c8 * 8) = v;
        }
    }
}

__device__ __forceinline__ void store_cols8(
    f32x4 acc[8][4], unsigned short* Vw, unsigned short* lw, int lane)
{
    const int lr = lane & 15, quad = lane >> 4;
    #pragma unroll
    for (int ip = 0; ip < 4; ++ip) {
        #pragma unroll
        for (int ii = 0; ii < 2; ++ii)
            #pragma unroll
            for (int j = 0; j < 4; ++j)
                #pragma unroll
                for (int r = 0; r < 4; ++r)
                    lw[(j * 16 + lr) * 40 + ii * 16 + quad * 4 + r] = f2b(acc[ip * 2 + ii][j][r]);
        #pragma unroll
        for (int t = 0; t < 4; ++t) {
            int chunk = t * 64 + lane;
            int col = chunk >> 2, c8 = chunk & 3;
            uint4 v = *(const uint4*)(lw + col * 40 + c8 * 8);
            *(uint4*)(Vw + col * SEQ + ip * 32 + c8 * 8) = v;
        }
    }
}

__device__ __forceinline__ void store_rows4(
    f32x4 acc[4][4], unsigned short* Cw, int ld, unsigned short* lw, int lane)
{
    const int lr = lane & 15, quad = lane >> 4;
    #pragma unroll
    for (int i = 0; i < 4; ++i) {
        #pragma unroll
        for (int j = 0; j < 4; ++j)
            #pragma unroll
            for (int r = 0; r < 4; ++r)
                lw[(quad * 4 + r) * 72 + j * 16 + lr] = f2b(acc[i][j][r]);
        #pragma unroll
        for (int t = 0; t < 2; ++t) {
            int chunk = t * 64 + lane;
            int rl = chunk >> 3, c8 = chunk & 7;
            uint4 v = *(const uint4*)(lw + rl * 72 + c8 * 8);
            *(uint4*)(Cw + (16 * i + rl) * ld + c8 * 8) = v;
        }
    }
}

// ---------------------------------------------------------------------------
// r1-proven 128^2 pieces for pv (4 waves, 256 thr).
// ---------------------------------------------------------------------------
__device__ __forceinline__ void stage_tiles4(
    const unsigned short* Ag, int lda, const unsigned short* Bg, int ldb,
    int k0, unsigned short* sA, unsigned short* sB, int wave, int lane)
{
    #pragma unroll
    for (int i = 0; i < 2; ++i) {
        int c = wave * 128 + i * 64 + lane;
        int row = c >> 2, slot = c & 3;
        int p = slot ^ ((row >> 1) & 3);
        gld_lds16(Ag + row * lda + k0 + p * 8, sA + (wave * 2 + i) * 512);
        gld_lds16(Bg + row * ldb + k0 + p * 8, sB + (wave * 2 + i) * 512);
    }
}

__device__ __forceinline__ void compute_tile4(
    const unsigned short* sA, const unsigned short* sB, f32x4 acc[4][4],
    int wm, int wn, int lr, int quad)
{
    bf16x8 af[4], bq[4];
    #pragma unroll
    for (int i = 0; i < 4; ++i)
        af[i] = *(const bf16x8*)frag_addr(sA, wm + 16 * i + lr, quad);
    #pragma unroll
    for (int j = 0; j < 4; ++j)
        bq[j] = *(const bf16x8*)frag_addr(sB, wn + 16 * j + lr, quad);
    #pragma unroll
    for (int i = 0; i < 4; ++i)
        #pragma unroll
        for (int j = 0; j < 4; ++j)
            acc[i][j] = __builtin_amdgcn_mfma_f32_16x16x32_bf16(af[i], bq[j], acc[i][j], 0, 0, 0);
}

__device__ __forceinline__ void mfma_db(
    const unsigned short* Ag, int lda, const unsigned short* Bg, int ldb,
    int kLen, unsigned short* lds, f32x4 acc[4][4])
{
    const int tid  = threadIdx.x;
    const int wave = tid >> 6, lane = tid & 63;
    const int lr   = lane & 15, quad = lane >> 4;
    const int wm   = (wave >> 1) * 64, wn = (wave & 1) * 64;
    unsigned short* sA0 = lds;
    unsigned short* sB0 = lds + 4096;
    unsigned short* sA1 = lds + 8192;
    unsigned short* sB1 = lds + 12288;

    stage_tiles4(Ag, lda, Bg, ldb, 0, sA0, sB0, wave, lane);
    int k = BK;
    #pragma unroll 1
    for (; k + BK < kLen; k += 2 * BK) {
        __syncthreads();
        stage_tiles4(Ag, lda, Bg, ldb, k, sA1, sB1, wave, lane);
        compute_tile4(sA0, sB0, acc, wm, wn, lr, quad);
        __syncthreads();
        stage_tiles4(Ag, lda, Bg, ldb, k + BK, sA0, sB0, wave, lane);
        compute_tile4(sA1, sB1, acc, wm, wn, lr, quad);
    }
    if (k < kLen) {
        __syncthreads();
        stage_tiles4(Ag, lda, Bg, ldb, k, sA1, sB1, wave, lane);
        compute_tile4(sA0, sB0, acc, wm, wn, lr, quad);
        __syncthreads();
        compute_tile4(sA1, sB1, acc, wm, wn, lr, quad);
    } else {
        __syncthreads();
        compute_tile4(sA0, sB0, acc, wm, wn, lr, quad);
    }
}

// ---------------------------------------------------------------------------
// Kernel 0: prep. [0,4096): x->bf16; [4096,7168): W transpose.
// (out/lrow zeroing moved to hipMemsetAsync.)
// ---------------------------------------------------------------------------
__global__ __launch_bounds__(256) void prep(
    const float* __restrict__ x, unsigned short* __restrict__ Xb,
    const float* __restrict__ W, unsigned short* __restrict__ Wt)
{
    __shared__ float tile[32][33];
    const int b = blockIdx.x, tid = threadIdx.x;
    if (b < 4096) {
        int i = (b * 256 + tid) * 4;
        float4 v = *(const float4*)(x + i);
        ushort4 o;
        o.x = f2b(v.x); o.y = f2b(v.y); o.z = f2b(v.z); o.w = f2b(v.w);
        *(ushort4*)(Xb + i) = o;
    } else {
        const int bb = b - 4096;
        const int n0 = (bb % 96) * 32, k0 = (bb / 96) * 32;
        const int c = tid & 31, r0 = tid >> 5;
        #pragma unroll
        for (int r = r0; r < 32; r += 8)
            tile[r][c] = W[(k0 + r) * NQKV + n0 + c];
        __syncthreads();
        #pragma unroll
        for (int r = r0; r < 32; r += 8)
            Wt[(n0 + r) * KDIM + k0 + c] = f2b(tile[c][r]);
    }
}

// ---------------------------------------------------------------------------
// Kernel 1: qvk = Xb @ Wt^T (256^2 8-phase). Grid (16,12).
// ---------------------------------------------------------------------------
__global__ __launch_bounds__(512, 2) void qvk_gemm(
    const unsigned short* __restrict__ Xb, const unsigned short* __restrict__ Wt,
    unsigned short* __restrict__ Qb, unsigned short* __restrict__ Kb,
    unsigned short* __restrict__ Vt)
{
    __shared__ __align__(16) unsigned short lds[65536];   // 128 KiB
    const int m0 = blockIdx.x * 256;
    const int n0 = blockIdx.y * 256;
    f32x4 acc[8][4];
    zero_acc8(acc);
    mfma_pipe8(Xb + m0 * KDIM, KDIM, Wt + n0 * KDIM, KDIM, lds, acc);
    __syncthreads();

    const int lane = threadIdx.x & 63, wave = threadIdx.x >> 6;
    const int wm = (wave >> 2) * 128, wn = (wave & 3) * 64;
    unsigned short* lw = lds + wave * 2560;
    const int region = n0 >> 10;            // 0:Q  1:V  2:K
    const int nloc = n0 & 1023;
    if (region == 0)
        store_rows8(acc, Qb + (m0 + wm) * KDIM + nloc + wn, KDIM, lw, lane);
    else if (region == 2)
        store_rows8(acc, Kb + (m0 + wm) * KDIM + nloc + wn, KDIM, lw, lane);
    else
        store_cols8(acc, Vt + (nloc + wn) * SEQ + m0 + wm, lw, lane);
}

// ---------------------------------------------------------------------------
// Kernel 2: fused score+exp (256^2 8-phase). Packed triangular grid: 136
// live blocks over 16x16 tiles. P=exp((Q@K^T)/32), causal; rowsum->lrow.
// ---------------------------------------------------------------------------
__global__ __launch_bounds__(512, 2) void score_exp_gemm(
    const unsigned short* __restrict__ Qb, const unsigned short* __restrict__ Kb,
    unsigned short* __restrict__ Sb, float* __restrict__ lrow)
{
    __shared__ __align__(16) unsigned short lds[65536];
    const int L = blockIdx.x;                   // 0..135
    int bm = (int)((sqrtf(8.0f * (float)L + 1.0f) - 1.0f) * 0.5f);
    while ((bm + 1) * (bm + 2) / 2 <= L) ++bm;
    while (bm * (bm + 1) / 2 > L) --bm;
    const int bn = L - bm * (bm + 1) / 2;
    const int m0 = bm * 256, n0 = bn * 256;

    f32x4 acc[8][4];
    zero_acc8(acc);
    mfma_pipe8(Qb + m0 * KDIM, KDIM, Kb + n0 * KDIM, KDIM, lds, acc);

    const int lane = threadIdx.x & 63, wave = threadIdx.x >> 6;
    const int lr = lane & 15, quad = lane >> 4;
    const int wm = (wave >> 2) * 128, wn = (wave & 3) * 64;
    #pragma unroll
    for (int i = 0; i < 8; ++i)
        #pragma unroll
        for (int j = 0; j < 4; ++j)
            #pragma unroll
            for (int r = 0; r < 4; ++r) {
                float v = __expf(acc[i][j][r] * 0.03125f);
                if (bm == bn) {
                    int row = wm + 16 * i + quad * 4 + r;
                    int col = wn + 16 * j + lr;
                    if (col > row) v = 0.f;
                }
                acc[i][j][r] = v;
            }
    #pragma unroll
    for (int i = 0; i < 8; ++i)
        #pragma unroll
        for (int r = 0; r < 4; ++r) {
            float s = acc[i][0][r] + acc[i][1][r] + acc[i][2][r] + acc[i][3][r];
            s += __shfl_xor(s, 1, 16);
            s += __shfl_xor(s, 2, 16);
            s += __shfl_xor(s, 4, 16);
            s += __shfl_xor(s, 8, 16);
            if (lr == 0)
                atomicAdd(&lrow[m0 + wm + 16 * i + quad * 4 + r], s);
        }
    __syncthreads();
    store_rows8(acc, Sb + (m0 + wm) * SEQ + n0 + wn, SEQ, lds + wave * 2560, lane);
}

// ---------------------------------------------------------------------------
// Kernel 3: pv — byte-exact r1 config (proven 47.8 us). 128^2, split-K 1024,
// atomic depth <=4, grid dim3(8, 80).
// ---------------------------------------------------------------------------
__global__ __launch_bounds__(256) void pv_gemm(
    const unsigned short* __restrict__ Sb, const unsigned short* __restrict__ Vt,
    const float* __restrict__ lrow, float* __restrict__ out)
{
    __shared__ __align__(16) unsigned short lds[16384];   // 32 KiB
    const int n0 = blockIdx.x * 128;
    const int y = blockIdx.y;               // 0..79
    int m, c;
    if (y < 8)       { m = y;                 c = 0; }
    else if (y < 24) { m = 8 + (y - 8) / 2;   c = (y - 8) % 2; }
    else if (y < 48) { m = 16 + (y - 24) / 3; c = (y - 24) % 3; }
    else             { m = 24 + (y - 48) / 4; c = (y - 48) % 4; }
    const int m0 = m * 128;
    const int kstart = c * 1024;
    const int kend = min((m + 1) * 128, kstart + 1024);
    const int nchunks = (m >> 3) + 1;

    f32x4 acc[4][4];
    zero_acc4(acc);
    mfma_db(Sb + m0 * SEQ + kstart, SEQ, Vt + n0 * SEQ + kstart, SEQ,
            kend - kstart, lds, acc);

    const int lane = threadIdx.x & 63, wave = threadIdx.x >> 6;
    const int lr = lane & 15, quad = lane >> 4;
    const int wm = (wave >> 1) * 64, wn = (wave & 1) * 64;
    #pragma unroll
    for (int i = 0; i < 4; ++i) {
        const int rbase = m0 + wm + 16 * i + quad * 4;
        const float4 l4 = *(const float4*)(lrow + rbase);
        float inv[4] = {1.0f / l4.x, 1.0f / l4.y, 1.0f / l4.z, 1.0f / l4.w};
        #pragma unroll
        for (int j = 0; j < 4; ++j) {
            const int col = n0 + wn + 16 * j + lr;
            if (nchunks == 1) {
                #pragma unroll
                for (int r = 0; r < 4; ++r)
                    out[(rbase + r) * KDIM + col] = acc[i][j][r] * inv[r];
            } else {
                #pragma unroll
                for (int r = 0; r < 4; ++r)
                    atomicAdd(&out[(rbase + r) * KDIM + col], acc[i][j][r] * inv[r]);
            }
        }
    }
}

// ---------------------------------------------------------------------------
extern "C" void kernel_launch(void* const* d_in, const int* in_sizes, int n_in,
                              void* d_out, int out_size, void* d_ws, size_t ws_size,
                              hipStream_t stream) {
    const float* x = (const float*)d_in[0];   // [4096][1024]
    const float* W = (const float*)d_in[1];   // [1024][3072]
    float* out = (float*)d_out;               // [4096][1024]
    char* ws = (char*)d_ws;

    unsigned short* Xb = (unsigned short*)(ws);                     //  8 MiB
    unsigned short* Wt = (unsigned short*)(ws + 8388608);           //  6 MiB
    unsigned short* Qb = (unsigned short*)(ws + 14680064);          //  8 MiB
    unsigned short* Kb = (unsigned short*)(ws + 23068672);          //  8 MiB
    unsigned short* Vt = (unsigned short*)(ws + 31457280);          //  8 MiB
    unsigned short* Sb = (unsigned short*)(ws + 39845888);          // 32 MiB
    float*        lrow = (float*)(ws + 73400320);                   // 16 KiB

    hipMemsetAsync(out, 0, (size_t)SEQ * KDIM * sizeof(float), stream);
    hipMemsetAsync(lrow, 0, (size_t)SEQ * sizeof(float), stream);
    prep          <<<7168, 256, 0, stream>>>(x, Xb, W, Wt);
    qvk_gemm      <<<dim3(SEQ / 256, NQKV / 256), 512, 0, stream>>>(Xb, Wt, Qb, Kb, Vt);
    score_exp_gemm<<<136, 512, 0, stream>>>(Qb, Kb, Sb, lrow);
    pv_gemm       <<<dim3(KDIM / 128, 80), 256, 0, stream>>>(Sb, Vt, lrow, out);
}

// Round 6
// 197.871 us; speedup vs baseline: 1.1218x; 1.0009x over previous
//
#include <hip/hip_runtime.h>

#define SEQ 4096
#define KDIM 1024
#define NQKV 3072
#define BK 32

typedef __bf16 bf16x8 __attribute__((ext_vector_type(8)));
typedef float  f32x4  __attribute__((ext_vector_type(4)));

#define WAITV(n) asm volatile("s_waitcnt vmcnt(" #n ")" ::: "memory")
#define BAR()    asm volatile("s_barrier" ::: "memory")

__device__ __forceinline__ unsigned short f2b(float f) {
    unsigned int u = __float_as_uint(f);
    u += 0x7FFFu + ((u >> 16) & 1u);   // round-to-nearest-even
    return (unsigned short)(u >> 16);
}

__device__ __forceinline__ void gld_lds16(const unsigned short* g, unsigned short* l) {
    __builtin_amdgcn_global_load_lds(
        (const __attribute__((address_space(1))) void*)g,
        (__attribute__((address_space(3))) void*)l, 16, 0, 0);
}

// ---------------------------------------------------------------------------
// Proven 128x128 pieces (r1): XOR-swizzled staging + fragment reads + MFMA.
// ---------------------------------------------------------------------------
__device__ __forceinline__ void stage_tiles(
    const unsigned short* Ag, int lda, const unsigned short* Bg, int ldb,
    int k0, unsigned short* sA, unsigned short* sB, int wave, int lane)
{
    #pragma unroll
    for (int i = 0; i < 2; ++i) {
        int c = wave * 128 + i * 64 + lane;        // chunk id 0..511
        int row = c >> 2, slot = c & 3;
        int p = slot ^ ((row >> 1) & 3);           // XOR-swizzled piece
        gld_lds16(Ag + row * lda + k0 + p * 8, sA + (wave * 2 + i) * 512);
        gld_lds16(Bg + row * ldb + k0 + p * 8, sB + (wave * 2 + i) * 512);
    }
}

__device__ __forceinline__ const unsigned short* frag_addr(
    const unsigned short* s, int row, int quad)
{
    return s + row * 32 + (quad ^ ((row >> 1) & 3)) * 8;
}

__device__ __forceinline__ void compute_tile(
    const unsigned short* sA, const unsigned short* sB, f32x4 acc[4][4],
    int wm, int wn, int lr, int quad)
{
    bf16x8 af[4], bq[4];
    #pragma unroll
    for (int i = 0; i < 4; ++i)
        af[i] = *(const bf16x8*)frag_addr(sA, wm + 16 * i + lr, quad);
    #pragma unroll
    for (int j = 0; j < 4; ++j)
        bq[j] = *(const bf16x8*)frag_addr(sB, wn + 16 * j + lr, quad);
    #pragma unroll
    for (int i = 0; i < 4; ++i)
        #pragma unroll
        for (int j = 0; j < 4; ++j)
            acc[i][j] = __builtin_amdgcn_mfma_f32_16x16x32_bf16(af[i], bq[j], acc[i][j], 0, 0, 0);
}

// 3-stage vmcnt-gated pipe (48 KB LDS) — for the K=1024 GEMMs (qvk, score).
__device__ __forceinline__ void mfma_pipe(
    const unsigned short* Ag, int lda, const unsigned short* Bg, int ldb,
    int kLen, unsigned short* lds, f32x4 acc[4][4])
{
    const int tid  = threadIdx.x;
    const int wave = tid >> 6, lane = tid & 63;
    const int lr   = lane & 15, quad = lane >> 4;
    const int wm   = (wave >> 1) * 64, wn = (wave & 1) * 64;
    const int niter = kLen >> 5;

    #pragma unroll
    for (int s = 0; s < 2; ++s)
        if (s < niter)
            stage_tiles(Ag, lda, Bg, ldb, s * BK,
                        lds + s * 8192, lds + s * 8192 + 4096, wave, lane);

    #pragma unroll 1
    for (int k = 0; k < niter; ++k) {
        if (k + 1 < niter) WAITV(4);    // stage k done; k+1 stays in flight
        else               WAITV(0);
        BAR();
        if (k + 2 < niter) {
            const int s = (k + 2) % 3;
            stage_tiles(Ag, lda, Bg, ldb, (k + 2) * BK,
                        lds + s * 8192, lds + s * 8192 + 4096, wave, lane);
        }
        const int c = k % 3;
        compute_tile(lds + c * 8192, lds + c * 8192 + 4096, acc, wm, wn, lr, quad);
    }
}

// 2-stage __syncthreads double-buffer (32 KB LDS) — for pv.
__device__ __forceinline__ void mfma_db(
    const unsigned short* Ag, int lda, const unsigned short* Bg, int ldb,
    int kLen, unsigned short* lds, f32x4 acc[4][4])
{
    const int tid  = threadIdx.x;
    const int wave = tid >> 6, lane = tid & 63;
    const int lr   = lane & 15, quad = lane >> 4;
    const int wm   = (wave >> 1) * 64, wn = (wave & 1) * 64;
    unsigned short* sA0 = lds;
    unsigned short* sB0 = lds + 4096;
    unsigned short* sA1 = lds + 8192;
    unsigned short* sB1 = lds + 12288;

    stage_tiles(Ag, lda, Bg, ldb, 0, sA0, sB0, wave, lane);
    int k = BK;
    #pragma unroll 1
    for (; k + BK < kLen; k += 2 * BK) {
        __syncthreads();
        stage_tiles(Ag, lda, Bg, ldb, k, sA1, sB1, wave, lane);
        compute_tile(sA0, sB0, acc, wm, wn, lr, quad);
        __syncthreads();
        stage_tiles(Ag, lda, Bg, ldb, k + BK, sA0, sB0, wave, lane);
        compute_tile(sA1, sB1, acc, wm, wn, lr, quad);
    }
    if (k < kLen) {
        __syncthreads();
        stage_tiles(Ag, lda, Bg, ldb, k, sA1, sB1, wave, lane);
        compute_tile(sA0, sB0, acc, wm, wn, lr, quad);
        __syncthreads();
        compute_tile(sA1, sB1, acc, wm, wn, lr, quad);
    } else {
        __syncthreads();
        compute_tile(sA0, sB0, acc, wm, wn, lr, quad);
    }
}

__device__ __forceinline__ void zero_acc(f32x4 acc[4][4]) {
    const f32x4 z = {0.f, 0.f, 0.f, 0.f};
    #pragma unroll
    for (int i = 0; i < 4; ++i)
        #pragma unroll
        for (int j = 0; j < 4; ++j) acc[i][j] = z;
}

// ---------------------------------------------------------------------------
// Epilogue: wave-private LDS restage -> 16B coalesced bf16 stores.
// ---------------------------------------------------------------------------
__device__ __forceinline__ void store_rows_bf16(
    f32x4 acc[4][4], unsigned short* Cw, int ld, unsigned short* lw, int lane)
{
    const int lr = lane & 15, quad = lane >> 4;
    #pragma unroll
    for (int i = 0; i < 4; ++i) {
        #pragma unroll
        for (int j = 0; j < 4; ++j)
            #pragma unroll
            for (int r = 0; r < 4; ++r)
                lw[(quad * 4 + r) * 72 + j * 16 + lr] = f2b(acc[i][j][r]);
        #pragma unroll
        for (int t = 0; t < 2; ++t) {
            int chunk = t * 64 + lane;          // 0..127
            int rl = chunk >> 3, c8 = chunk & 7;
            uint4 v = *(const uint4*)(lw + rl * 72 + c8 * 8);
            *(uint4*)(Cw + (16 * i + rl) * ld + c8 * 8) = v;
        }
    }
}

// Transposed (Vt[d][s]): each lane stores 8 consecutive s for one d.
__device__ __forceinline__ void store_cols_bf16(
    f32x4 acc[4][4], unsigned short* Vw, unsigned short* lw, int lane)
{
    const int lr = lane & 15, quad = lane >> 4;
    #pragma unroll
    for (int ip = 0; ip < 2; ++ip) {            // 32 s-rows per pass
        #pragma unroll
        for (int ii = 0; ii < 2; ++ii)
            #pragma unroll
            for (int j = 0; j < 4; ++j)
                #pragma unroll
                for (int r = 0; r < 4; ++r)
                    lw[(j * 16 + lr) * 40 + ii * 16 + quad * 4 + r] = f2b(acc[ip * 2 + ii][j][r]);
        #pragma unroll
        for (int t = 0; t < 4; ++t) {
            int chunk = t * 64 + lane;          // 0..255
            int col = chunk >> 2, c8 = chunk & 3;
            uint4 v = *(const uint4*)(lw + col * 40 + c8 * 8);
            *(uint4*)(Vw + col * SEQ + ip * 32 + c8 * 8) = v;
        }
    }
}

// ---------------------------------------------------------------------------
// Kernel 0: prep. [0,4096): x->bf16; [4096,7168): W transpose.
// (out/lrow zeroing via hipMemsetAsync — r5-proven, saved ~25 us.)
// ---------------------------------------------------------------------------
__global__ __launch_bounds__(256) void prep(
    const float* __restrict__ x, unsigned short* __restrict__ Xb,
    const float* __restrict__ W, unsigned short* __restrict__ Wt)
{
    __shared__ float tile[32][33];
    const int b = blockIdx.x, tid = threadIdx.x;
    if (b < 4096) {
        int i = (b * 256 + tid) * 4;
        float4 v = *(const float4*)(x + i);
        ushort4 o;
        o.x = f2b(v.x); o.y = f2b(v.y); o.z = f2b(v.z); o.w = f2b(v.w);
        *(ushort4*)(Xb + i) = o;
    } else {
        const int bb = b - 4096;
        const int n0 = (bb % 96) * 32, k0 = (bb / 96) * 32;
        const int c = tid & 31, r0 = tid >> 5;
        #pragma unroll
        for (int r = r0; r < 32; r += 8)
            tile[r][c] = W[(k0 + r) * NQKV + n0 + c];
        __syncthreads();
        #pragma unroll
        for (int r = r0; r < 32; r += 8)
            Wt[(n0 + r) * KDIM + k0 + c] = f2b(tile[c][r]);
    }
}

// ---------------------------------------------------------------------------
// Kernel 1: qvk = Xb @ Wt^T -> Q rows, K rows, V transposed (Vt[d][s])
// r1-proven: 128^2 tiles, grid (32, 24), 3 blocks/CU co-resident.
// ---------------------------------------------------------------------------
__global__ __launch_bounds__(256) void qvk_gemm(
    const unsigned short* __restrict__ Xb, const unsigned short* __restrict__ Wt,
    unsigned short* __restrict__ Qb, unsigned short* __restrict__ Kb,
    unsigned short* __restrict__ Vt)
{
    __shared__ __align__(16) unsigned short lds[24576];   // 48 KiB
    const int m0 = blockIdx.x * 128;
    const int n0 = blockIdx.y * 128;
    f32x4 acc[4][4];
    zero_acc(acc);
    mfma_pipe(Xb + m0 * KDIM, KDIM, Wt + n0 * KDIM, KDIM, KDIM, lds, acc);
    __syncthreads();

    const int lane = threadIdx.x & 63, wave = threadIdx.x >> 6;
    const int wm = (wave >> 1) * 64, wn = (wave & 1) * 64;
    unsigned short* lw = lds + wave * 2560;
    const int region = n0 >> 10;            // 0:Q  1:V  2:K
    const int nloc = n0 & 1023;
    if (region == 0)
        store_rows_bf16(acc, Qb + (m0 + wm) * KDIM + nloc + wn, KDIM, lw, lane);
    else if (region == 2)
        store_rows_bf16(acc, Kb + (m0 + wm) * KDIM + nloc + wn, KDIM, lw, lane);
    else
        store_cols_bf16(acc, Vt + (nloc + wn) * SEQ + m0 + wm, lw, lane);
}

// ---------------------------------------------------------------------------
// Kernel 2: fused score+exp. P = exp((Q@K^T)/32) causal (no max-sub: |s|<=16
// by Cauchy-Schwarz). Row sums atomicAdd into lrow; P bf16 to Sb.
// Packed triangular 1-D grid: exactly 528 live 128^2 tiles (r4-proven).
// ---------------------------------------------------------------------------
__global__ __launch_bounds__(256) void score_exp_gemm(
    const unsigned short* __restrict__ Qb, const unsigned short* __restrict__ Kb,
    unsigned short* __restrict__ Sb, float* __restrict__ lrow)
{
    __shared__ __align__(16) unsigned short lds[24576];
    const int L = blockIdx.x;                   // 0..527
    int bm = (int)((sqrtf(8.0f * (float)L + 1.0f) - 1.0f) * 0.5f);
    while ((bm + 1) * (bm + 2) / 2 <= L) ++bm;  // fix float rounding
    while (bm * (bm + 1) / 2 > L) --bm;
    const int bn = L - bm * (bm + 1) / 2;
    const int m0 = bm * 128, n0 = bn * 128;

    f32x4 acc[4][4];
    zero_acc(acc);
    mfma_pipe(Qb + m0 * KDIM, KDIM, Kb + n0 * KDIM, KDIM, KDIM, lds, acc);

    const int lane = threadIdx.x & 63, wave = threadIdx.x >> 6;
    const int lr = lane & 15, quad = lane >> 4;
    const int wm = (wave >> 1) * 64, wn = (wave & 1) * 64;
    #pragma unroll
    for (int i = 0; i < 4; ++i)
        #pragma unroll
        for (int j = 0; j < 4; ++j)
            #pragma unroll
            for (int r = 0; r < 4; ++r) {
                float v = __expf(acc[i][j][r] * 0.03125f);
                if (bm == bn) {
                    int row = wm + 16 * i + quad * 4 + r;
                    int col = wn + 16 * j + lr;
                    if (col > row) v = 0.f;
                }
                acc[i][j][r] = v;
            }
    #pragma unroll
    for (int i = 0; i < 4; ++i)
        #pragma unroll
        for (int r = 0; r < 4; ++r) {
            float s = acc[i][0][r] + acc[i][1][r] + acc[i][2][r] + acc[i][3][r];
            s += __shfl_xor(s, 1, 16);
            s += __shfl_xor(s, 2, 16);
            s += __shfl_xor(s, 4, 16);
            s += __shfl_xor(s, 8, 16);
            if (lr == 0)
                atomicAdd(&lrow[m0 + wm + 16 * i + quad * 4 + r], s);
        }
    __syncthreads();
    store_rows_bf16(acc, Sb + (m0 + wm) * SEQ + n0 + wn, SEQ, lds + wave * 2560, lane);
}

// ---------------------------------------------------------------------------
// Kernel 3: out = (P @ V) / l, split-K in 1024-wide chunks (atomic depth <=4).
// r1-proven: grid dim3(8, 80) = 640 blocks, 5 blocks/CU LDS-fit.
// ---------------------------------------------------------------------------
__global__ __launch_bounds__(256) void pv_gemm(
    const unsigned short* __restrict__ Sb, const unsigned short* __restrict__ Vt,
    const float* __restrict__ lrow, float* __restrict__ out)
{
    __shared__ __align__(16) unsigned short lds[16384];   // 32 KiB
    const int n0 = blockIdx.x * 128;
    const int y = blockIdx.y;               // 0..79
    int m, c;
    if (y < 8)       { m = y;                 c = 0; }
    else if (y < 24) { m = 8 + (y - 8) / 2;   c = (y - 8) % 2; }
    else if (y < 48) { m = 16 + (y - 24) / 3; c = (y - 24) % 3; }
    else             { m = 24 + (y - 48) / 4; c = (y - 48) % 4; }
    const int m0 = m * 128;
    const int kstart = c * 1024;
    const int kend = min((m + 1) * 128, kstart + 1024);
    const int nchunks = (m >> 3) + 1;

    f32x4 acc[4][4];
    zero_acc(acc);
    mfma_db(Sb + m0 * SEQ + kstart, SEQ, Vt + n0 * SEQ + kstart, SEQ,
            kend - kstart, lds, acc);

    const int lane = threadIdx.x & 63, wave = threadIdx.x >> 6;
    const int lr = lane & 15, quad = lane >> 4;
    const int wm = (wave >> 1) * 64, wn = (wave & 1) * 64;
    #pragma unroll
    for (int i = 0; i < 4; ++i) {
        const int rbase = m0 + wm + 16 * i + quad * 4;
        const float4 l4 = *(const float4*)(lrow + rbase);
        float inv[4] = {1.0f / l4.x, 1.0f / l4.y, 1.0f / l4.z, 1.0f / l4.w};
        #pragma unroll
        for (int j = 0; j < 4; ++j) {
            const int col = n0 + wn + 16 * j + lr;
            if (nchunks == 1) {
                #pragma unroll
                for (int r = 0; r < 4; ++r)
                    out[(rbase + r) * KDIM + col] = acc[i][j][r] * inv[r];
            } else {
                #pragma unroll
                for (int r = 0; r < 4; ++r)
                    atomicAdd(&out[(rbase + r) * KDIM + col], acc[i][j][r] * inv[r]);
            }
        }
    }
}

// ---------------------------------------------------------------------------
extern "C" void kernel_launch(void* const* d_in, const int* in_sizes, int n_in,
                              void* d_out, int out_size, void* d_ws, size_t ws_size,
                              hipStream_t stream) {
    const float* x = (const float*)d_in[0];   // [4096][1024]
    const float* W = (const float*)d_in[1];   // [1024][3072]
    float* out = (float*)d_out;               // [4096][1024]
    char* ws = (char*)d_ws;

    unsigned short* Xb = (unsigned short*)(ws);                     //  8 MiB
    unsigned short* Wt = (unsigned short*)(ws + 8388608);           //  6 MiB
    unsigned short* Qb = (unsigned short*)(ws + 14680064);          //  8 MiB
    unsigned short* Kb = (unsigned short*)(ws + 23068672);          //  8 MiB
    unsigned short* Vt = (unsigned short*)(ws + 31457280);          //  8 MiB
    unsigned short* Sb = (unsigned short*)(ws + 39845888);          // 32 MiB
    float*        lrow = (float*)(ws + 73400320);                   // 16 KiB

    hipMemsetAsync(out, 0, (size_t)SEQ * KDIM * sizeof(float), stream);
    hipMemsetAsync(lrow, 0, (size_t)SEQ * sizeof(float), stream);
    prep          <<<7168, 256, 0, stream>>>(x, Xb, W, Wt);
    qvk_gemm      <<<dim3(SEQ / 128, NQKV / 128), 256, 0, stream>>>(Xb, Wt, Qb, Kb, Vt);
    score_exp_gemm<<<528, 256, 0, stream>>>(Qb, Kb, Sb, lrow);
    pv_gemm       <<<dim3(KDIM / 128, 80), 256, 0, stream>>>(Sb, Vt, lrow, out);
}

// Round 10
// 193.370 us; speedup vs baseline: 1.1479x; 1.0233x over previous
//
#include <hip/hip_runtime.h>

#define SEQ 4096
#define KDIM 1024
#define NQKV 3072
#define BK 32

typedef __bf16 bf16x8 __attribute__((ext_vector_type(8)));
typedef float  f32x4  __attribute__((ext_vector_type(4)));

#define WAITV(n) asm volatile("s_waitcnt vmcnt(" #n ")" ::: "memory")
#define BAR()    asm volatile("s_barrier" ::: "memory")

__device__ __forceinline__ unsigned short f2b(float f) {
    unsigned int u = __float_as_uint(f);
    u += 0x7FFFu + ((u >> 16) & 1u);   // round-to-nearest-even
    return (unsigned short)(u >> 16);
}

__device__ __forceinline__ void gld_lds16(const unsigned short* g, unsigned short* l) {
    __builtin_amdgcn_global_load_lds(
        (const __attribute__((address_space(1))) void*)g,
        (__attribute__((address_space(3))) void*)l, 16, 0, 0);
}

// ---------------------------------------------------------------------------
// Proven 128x128 pieces (r1/r6): XOR-swizzled staging + fragments + MFMA.
// ---------------------------------------------------------------------------
__device__ __forceinline__ void stage_tiles(
    const unsigned short* Ag, int lda, const unsigned short* Bg, int ldb,
    int k0, unsigned short* sA, unsigned short* sB, int wave, int lane)
{
    #pragma unroll
    for (int i = 0; i < 2; ++i) {
        int c = wave * 128 + i * 64 + lane;        // chunk id 0..511
        int row = c >> 2, slot = c & 3;
        int p = slot ^ ((row >> 1) & 3);           // XOR-swizzled piece
        gld_lds16(Ag + row * lda + k0 + p * 8, sA + (wave * 2 + i) * 512);
        gld_lds16(Bg + row * ldb + k0 + p * 8, sB + (wave * 2 + i) * 512);
    }
}

__device__ __forceinline__ const unsigned short* frag_addr(
    const unsigned short* s, int row, int quad)
{
    return s + row * 32 + (quad ^ ((row >> 1) & 3)) * 8;
}

__device__ __forceinline__ void compute_tile(
    const unsigned short* sA, const unsigned short* sB, f32x4 acc[4][4],
    int wm, int wn, int lr, int quad)
{
    bf16x8 af[4], bq[4];
    #pragma unroll
    for (int i = 0; i < 4; ++i)
        af[i] = *(const bf16x8*)frag_addr(sA, wm + 16 * i + lr, quad);
    #pragma unroll
    for (int j = 0; j < 4; ++j)
        bq[j] = *(const bf16x8*)frag_addr(sB, wn + 16 * j + lr, quad);
    #pragma unroll
    for (int i = 0; i < 4; ++i)
        #pragma unroll
        for (int j = 0; j < 4; ++j)
            acc[i][j] = __builtin_amdgcn_mfma_f32_16x16x32_bf16(af[i], bq[j], acc[i][j], 0, 0, 0);
}

// 3-stage vmcnt-gated pipe (48 KB LDS) — for the K=1024 GEMMs (qvk, score).
__device__ __forceinline__ void mfma_pipe(
    const unsigned short* Ag, int lda, const unsigned short* Bg, int ldb,
    int kLen, unsigned short* lds, f32x4 acc[4][4])
{
    const int tid  = threadIdx.x;
    const int wave = tid >> 6, lane = tid & 63;
    const int lr   = lane & 15, quad = lane >> 4;
    const int wm   = (wave >> 1) * 64, wn = (wave & 1) * 64;
    const int niter = kLen >> 5;

    #pragma unroll
    for (int s = 0; s < 2; ++s)
        if (s < niter)
            stage_tiles(Ag, lda, Bg, ldb, s * BK,
                        lds + s * 8192, lds + s * 8192 + 4096, wave, lane);

    #pragma unroll 1
    for (int k = 0; k < niter; ++k) {
        if (k + 1 < niter) WAITV(4);    // stage k done; k+1 stays in flight
        else               WAITV(0);
        BAR();
        if (k + 2 < niter) {
            const int s = (k + 2) % 3;
            stage_tiles(Ag, lda, Bg, ldb, (k + 2) * BK,
                        lds + s * 8192, lds + s * 8192 + 4096, wave, lane);
        }
        const int c = k % 3;
        compute_tile(lds + c * 8192, lds + c * 8192 + 4096, acc, wm, wn, lr, quad);
    }
}

// 2-stage __syncthreads double-buffer (32 KB LDS) — for pv.
__device__ __forceinline__ void mfma_db(
    const unsigned short* Ag, int lda, const unsigned short* Bg, int ldb,
    int kLen, unsigned short* lds, f32x4 acc[4][4])
{
    const int tid  = threadIdx.x;
    const int wave = tid >> 6, lane = tid & 63;
    const int lr   = lane & 15, quad = lane >> 4;
    const int wm   = (wave >> 1) * 64, wn = (wave & 1) * 64;
    unsigned short* sA0 = lds;
    unsigned short* sB0 = lds + 4096;
    unsigned short* sA1 = lds + 8192;
    unsigned short* sB1 = lds + 12288;

    stage_tiles(Ag, lda, Bg, ldb, 0, sA0, sB0, wave, lane);
    int k = BK;
    #pragma unroll 1
    for (; k + BK < kLen; k += 2 * BK) {
        __syncthreads();
        stage_tiles(Ag, lda, Bg, ldb, k, sA1, sB1, wave, lane);
        compute_tile(sA0, sB0, acc, wm, wn, lr, quad);
        __syncthreads();
        stage_tiles(Ag, lda, Bg, ldb, k + BK, sA0, sB0, wave, lane);
        compute_tile(sA1, sB1, acc, wm, wn, lr, quad);
    }
    if (k < kLen) {
        __syncthreads();
        stage_tiles(Ag, lda, Bg, ldb, k, sA1, sB1, wave, lane);
        compute_tile(sA0, sB0, acc, wm, wn, lr, quad);
        __syncthreads();
        compute_tile(sA1, sB1, acc, wm, wn, lr, quad);
    } else {
        __syncthreads();
        compute_tile(sA0, sB0, acc, wm, wn, lr, quad);
    }
}

__device__ __forceinline__ void zero_acc(f32x4 acc[4][4]) {
    const f32x4 z = {0.f, 0.f, 0.f, 0.f};
    #pragma unroll
    for (int i = 0; i < 4; ++i)
        #pragma unroll
        for (int j = 0; j < 4; ++j) acc[i][j] = z;
}

// ---------------------------------------------------------------------------
// Epilogue: wave-private LDS restage -> 16B coalesced bf16 stores.
// ---------------------------------------------------------------------------
__device__ __forceinline__ void store_rows_bf16(
    f32x4 acc[4][4], unsigned short* Cw, int ld, unsigned short* lw, int lane)
{
    const int lr = lane & 15, quad = lane >> 4;
    #pragma unroll
    for (int i = 0; i < 4; ++i) {
        #pragma unroll
        for (int j = 0; j < 4; ++j)
            #pragma unroll
            for (int r = 0; r < 4; ++r)
                lw[(quad * 4 + r) * 72 + j * 16 + lr] = f2b(acc[i][j][r]);
        #pragma unroll
        for (int t = 0; t < 2; ++t) {
            int chunk = t * 64 + lane;          // 0..127
            int rl = chunk >> 3, c8 = chunk & 7;
            uint4 v = *(const uint4*)(lw + rl * 72 + c8 * 8);
            *(uint4*)(Cw + (16 * i + rl) * ld + c8 * 8) = v;
        }
    }
}

// Transposed (Vt[d][s]): each lane stores 8 consecutive s for one d.
__device__ __forceinline__ void store_cols_bf16(
    f32x4 acc[4][4], unsigned short* Vw, unsigned short* lw, int lane)
{
    const int lr = lane & 15, quad = lane >> 4;
    #pragma unroll
    for (int ip = 0; ip < 2; ++ip) {            // 32 s-rows per pass
        #pragma unroll
        for (int ii = 0; ii < 2; ++ii)
            #pragma unroll
            for (int j = 0; j < 4; ++j)
                #pragma unroll
                for (int r = 0; r < 4; ++r)
                    lw[(j * 16 + lr) * 40 + ii * 16 + quad * 4 + r] = f2b(acc[ip * 2 + ii][j][r]);
        #pragma unroll
        for (int t = 0; t < 4; ++t) {
            int chunk = t * 64 + lane;          // 0..255
            int col = chunk >> 2, c8 = chunk & 3;
            uint4 v = *(const uint4*)(lw + col * 40 + c8 * 8);
            *(uint4*)(Vw + col * SEQ + ip * 32 + c8 * 8) = v;
        }
    }
}

// ---------------------------------------------------------------------------
// Kernel 0: fused prep (4 dispatch-node layout — memsets folded back in).
// [0,4096): x->bf16; [4096,7168): W transpose; [7168,8192): zero out;
// block 8192: zero lrow[4096].
// ---------------------------------------------------------------------------
__global__ __launch_bounds__(256) void prep(
    const float* __restrict__ x, unsigned short* __restrict__ Xb,
    const float* __restrict__ W, unsigned short* __restrict__ Wt,
    float4* __restrict__ out4, float4* __restrict__ lrow4)
{
    __shared__ float tile[32][33];
    const int b = blockIdx.x, tid = threadIdx.x;
    if (b < 4096) {
        int i = (b * 256 + tid) * 4;
        float4 v = *(const float4*)(x + i);
        ushort4 o;
        o.x = f2b(v.x); o.y = f2b(v.y); o.z = f2b(v.z); o.w = f2b(v.w);
        *(ushort4*)(Xb + i) = o;
    } else if (b < 7168) {
        const int bb = b - 4096;
        const int n0 = (bb % 96) * 32, k0 = (bb / 96) * 32;
        const int c = tid & 31, r0 = tid >> 5;
        #pragma unroll
        for (int r = r0; r < 32; r += 8)
            tile[r][c] = W[(k0 + r) * NQKV + n0 + c];
        __syncthreads();
        #pragma unroll
        for (int r = r0; r < 32; r += 8)
            Wt[(n0 + r) * KDIM + k0 + c] = f2b(tile[c][r]);
    } else if (b < 8192) {
        const int base = (b - 7168) * 1024;     // 1024 float4 per block
        const float4 z = {0.f, 0.f, 0.f, 0.f};
        #pragma unroll
        for (int k = 0; k < 4; ++k)
            out4[base + k * 256 + tid] = z;
    } else {
        const float4 z = {0.f, 0.f, 0.f, 0.f};
        #pragma unroll
        for (int k = 0; k < 4; ++k) lrow4[k * 256 + tid] = z;
    }
}

// ---------------------------------------------------------------------------
// Kernel 1: qvk = Xb @ Wt^T -> Q rows, K rows, V transposed (Vt[d][s])
// r1/r6-proven: 128^2 tiles, grid (32, 24), 3 blocks/CU co-resident.
// ---------------------------------------------------------------------------
__global__ __launch_bounds__(256) void qvk_gemm(
    const unsigned short* __restrict__ Xb, const unsigned short* __restrict__ Wt,
    unsigned short* __restrict__ Qb, unsigned short* __restrict__ Kb,
    unsigned short* __restrict__ Vt)
{
    __shared__ __align__(16) unsigned short lds[24576];   // 48 KiB
    const int m0 = blockIdx.x * 128;
    const int n0 = blockIdx.y * 128;
    f32x4 acc[4][4];
    zero_acc(acc);
    mfma_pipe(Xb + m0 * KDIM, KDIM, Wt + n0 * KDIM, KDIM, KDIM, lds, acc);
    __syncthreads();

    const int lane = threadIdx.x & 63, wave = threadIdx.x >> 6;
    const int wm = (wave >> 1) * 64, wn = (wave & 1) * 64;
    unsigned short* lw = lds + wave * 2560;
    const int region = n0 >> 10;            // 0:Q  1:V  2:K
    const int nloc = n0 & 1023;
    if (region == 0)
        store_rows_bf16(acc, Qb + (m0 + wm) * KDIM + nloc + wn, KDIM, lw, lane);
    else if (region == 2)
        store_rows_bf16(acc, Kb + (m0 + wm) * KDIM + nloc + wn, KDIM, lw, lane);
    else
        store_cols_bf16(acc, Vt + (nloc + wn) * SEQ + m0 + wm, lw, lane);
}

// ---------------------------------------------------------------------------
// Kernel 2: fused score+exp. P = exp((Q@K^T)/32) causal (no max-sub: |s|<=16
// by Cauchy-Schwarz). Row sums atomicAdd into lrow; P bf16 to Sb.
// Packed triangular 1-D grid: exactly 528 live 128^2 tiles (r6-proven).
// ---------------------------------------------------------------------------
__global__ __launch_bounds__(256) void score_exp_gemm(
    const unsigned short* __restrict__ Qb, const unsigned short* __restrict__ Kb,
    unsigned short* __restrict__ Sb, float* __restrict__ lrow)
{
    __shared__ __align__(16) unsigned short lds[24576];
    const int L = blockIdx.x;                   // 0..527
    int bm = (int)((sqrtf(8.0f * (float)L + 1.0f) - 1.0f) * 0.5f);
    while ((bm + 1) * (bm + 2) / 2 <= L) ++bm;  // fix float rounding
    while (bm * (bm + 1) / 2 > L) --bm;
    const int bn = L - bm * (bm + 1) / 2;
    const int m0 = bm * 128, n0 = bn * 128;

    f32x4 acc[4][4];
    zero_acc(acc);
    mfma_pipe(Qb + m0 * KDIM, KDIM, Kb + n0 * KDIM, KDIM, KDIM, lds, acc);

    const int lane = threadIdx.x & 63, wave = threadIdx.x >> 6;
    const int lr = lane & 15, quad = lane >> 4;
    const int wm = (wave >> 1) * 64, wn = (wave & 1) * 64;
    #pragma unroll
    for (int i = 0; i < 4; ++i)
        #pragma unroll
        for (int j = 0; j < 4; ++j)
            #pragma unroll
            for (int r = 0; r < 4; ++r) {
                float v = __expf(acc[i][j][r] * 0.03125f);
                if (bm == bn) {
                    int row = wm + 16 * i + quad * 4 + r;
                    int col = wn + 16 * j + lr;
                    if (col > row) v = 0.f;
                }
                acc[i][j][r] = v;
            }
    #pragma unroll
    for (int i = 0; i < 4; ++i)
        #pragma unroll
        for (int r = 0; r < 4; ++r) {
            float s = acc[i][0][r] + acc[i][1][r] + acc[i][2][r] + acc[i][3][r];
            s += __shfl_xor(s, 1, 16);
            s += __shfl_xor(s, 2, 16);
            s += __shfl_xor(s, 4, 16);
            s += __shfl_xor(s, 8, 16);
            if (lr == 0)
                atomicAdd(&lrow[m0 + wm + 16 * i + quad * 4 + r], s);
        }
    __syncthreads();
    store_rows_bf16(acc, Sb + (m0 + wm) * SEQ + n0 + wn, SEQ, lds + wave * 2560, lane);
}

// ---------------------------------------------------------------------------
// Kernel 3: out = (P @ V) / l, split-K in 1024-wide chunks (atomic depth <=4).
// r1/r6-proven: grid dim3(8, 80) = 640 blocks, 5 blocks/CU LDS-fit.
// ---------------------------------------------------------------------------
__global__ __launch_bounds__(256) void pv_gemm(
    const unsigned short* __restrict__ Sb, const unsigned short* __restrict__ Vt,
    const float* __restrict__ lrow, float* __restrict__ out)
{
    __shared__ __align__(16) unsigned short lds[16384];   // 32 KiB
    const int n0 = blockIdx.x * 128;
    const int y = blockIdx.y;               // 0..79
    int m, c;
    if (y < 8)       { m = y;                 c = 0; }
    else if (y < 24) { m = 8 + (y - 8) / 2;   c = (y - 8) % 2; }
    else if (y < 48) { m = 16 + (y - 24) / 3; c = (y - 24) % 3; }
    else             { m = 24 + (y - 48) / 4; c = (y - 48) % 4; }
    const int m0 = m * 128;
    const int kstart = c * 1024;
    const int kend = min((m + 1) * 128, kstart + 1024);
    const int nchunks = (m >> 3) + 1;

    f32x4 acc[4][4];
    zero_acc(acc);
    mfma_db(Sb + m0 * SEQ + kstart, SEQ, Vt + n0 * SEQ + kstart, SEQ,
            kend - kstart, lds, acc);

    const int lane = threadIdx.x & 63, wave = threadIdx.x >> 6;
    const int lr = lane & 15, quad = lane >> 4;
    const int wm = (wave >> 1) * 64, wn = (wave & 1) * 64;
    #pragma unroll
    for (int i = 0; i < 4; ++i) {
        const int rbase = m0 + wm + 16 * i + quad * 4;
        const float4 l4 = *(const float4*)(lrow + rbase);
        float inv[4] = {1.0f / l4.x, 1.0f / l4.y, 1.0f / l4.z, 1.0f / l4.w};
        #pragma unroll
        for (int j = 0; j < 4; ++j) {
            const int col = n0 + wn + 16 * j + lr;
            if (nchunks == 1) {
                #pragma unroll
                for (int r = 0; r < 4; ++r)
                    out[(rbase + r) * KDIM + col] = acc[i][j][r] * inv[r];
            } else {
                #pragma unroll
                for (int r = 0; r < 4; ++r)
                    atomicAdd(&out[(rbase + r) * KDIM + col], acc[i][j][r] * inv[r]);
            }
        }
    }
}

// ---------------------------------------------------------------------------
extern "C" void kernel_launch(void* const* d_in, const int* in_sizes, int n_in,
                              void* d_out, int out_size, void* d_ws, size_t ws_size,
                              hipStream_t stream) {
    const float* x = (const float*)d_in[0];   // [4096][1024]
    const float* W = (const float*)d_in[1];   // [1024][3072]
    float* out = (float*)d_out;               // [4096][1024]
    char* ws = (char*)d_ws;

    unsigned short* Xb = (unsigned short*)(ws);                     //  8 MiB
    unsigned short* Wt = (unsigned short*)(ws + 8388608);           //  6 MiB
    unsigned short* Qb = (unsigned short*)(ws + 14680064);          //  8 MiB
    unsigned short* Kb = (unsigned short*)(ws + 23068672);          //  8 MiB
    unsigned short* Vt = (unsigned short*)(ws + 31457280);          //  8 MiB
    unsigned short* Sb = (unsigned short*)(ws + 39845888);          // 32 MiB
    float*        lrow = (float*)(ws + 73400320);                   // 16 KiB

    prep          <<<8193, 256, 0, stream>>>(x, Xb, W, Wt, (float4*)out, (float4*)lrow);
    qvk_gemm      <<<dim3(SEQ / 128, NQKV / 128), 256, 0, stream>>>(Xb, Wt, Qb, Kb, Vt);
    score_exp_gemm<<<528, 256, 0, stream>>>(Qb, Kb, Sb, lrow);
    pv_gemm       <<<dim3(KDIM / 128, 80), 256, 0, stream>>>(Sb, Vt, lrow, out);
}